// Round 2
// baseline (24.428 us; speedup 1.0000x reference)
//
#include <hip/hip_runtime.h>

// Problem geometry (f32):
//   x:   [8, 16, 3, 224, 224]
//   out: [8, 16, 224, 224, 3]  (permute 0,1,4,3,2)
// batch 0: y[0]=x[0]; y[t] = x[t] - 0.4*y[t-1] + 3   (elementwise c,h,w)
// batches 1..6: zeros
// batch 7: z[0]=0; z[t] = 3 - 0.4*z[t-1], broadcast over (w,h,c)
//
// Design (round 2):
//  - Tile blocks: all 48 loads (16t x 3c) issued independently up front ->
//    one HBM latency, recurrence fully in registers, direct stores (no LDS,
//    no barriers). Store address SET is 96-B clusters either way; lane order
//    doesn't matter for coalescing.
//  - Work balance: tile block = 98 KB traffic; fill blocks sized to ~96 KB
//    contiguous each. 196 + 700 = 896 blocks (~3.5/CU; harness fills show
//    write BW saturates even at 9% occupancy).

#define SP        150528    // 3*224*224 elements per (b,t) slice
#define TT        16
#define CH_STRIDE 50176     // 224*224
#define BSTRIDE   2408448   // 16*SP elements per batch

#define NWT    7            // w tiles (224/32)
#define NHT    28           // h tiles (224/8)
#define NTILES 196

#define FILL4   4214784     // 7 * 16*SP/4 float4s (batches 1..7)
#define TSLICE4 37632       // SP/4
#define NFILL   700
#define RFILL   6022        // ceil(FILL4/NFILL)

__global__ __launch_bounds__(256) void temporal_fused(
    const float* __restrict__ x, float* __restrict__ out)
{
    const int tid = threadIdx.x;
    const int bid = blockIdx.x;

    const bool is_tile = ((bid & 3) == 0) && (bid >> 2) < NTILES;

    if (is_tile) {
        // ------------- batch-0 recurrence, tile = 8h x 32w, 3c/thread -----
        const int tileid = bid >> 2;
        const int h0 = (tileid / NWT) * 8;
        const int w0 = (tileid % NWT) * 32;
        const int dw = tid & 31;       // w offset: 32 consecutive -> 128B rows
        const int hh = tid >> 5;       // h offset 0..7
        const int rbase = (h0 + hh) * 224 + w0 + dw;

        // all 48 loads independent -> single HBM latency
        float v[TT][3];
        #pragma unroll
        for (int t = 0; t < TT; ++t) {
            #pragma unroll
            for (int c = 0; c < 3; ++c)
                v[t][c] = x[t * SP + c * CH_STRIDE + rbase];
        }

        const int ob = (w0 + dw) * 672 + (h0 + hh) * 3;
        float y0 = v[0][0], y1 = v[0][1], y2 = v[0][2];
        out[ob + 0] = y0;
        out[ob + 1] = y1;
        out[ob + 2] = y2;
        #pragma unroll
        for (int t = 1; t < TT; ++t) {
            y0 = v[t][0] - 0.4f * y0 + 3.0f;
            y1 = v[t][1] - 0.4f * y1 + 3.0f;
            y2 = v[t][2] - 0.4f * y2 + 3.0f;
            const int o = t * SP + ob;
            out[o + 0] = y0;
            out[o + 1] = y1;
            out[o + 2] = y2;
        }
        return;
    }

    // ---------------- fill: batches 1..6 zeros, batch 7 broadcast z[t] ----
    const int tiles_before = min((bid + 3) >> 2, NTILES);
    const int fidx = bid - tiles_before;          // 0..NFILL-1

    float4* out4 = reinterpret_cast<float4*>(out + BSTRIDE); // batch-1 start
    int q   = fidx * RFILL;
    int end = q + RFILL;
    if (end > FILL4) end = FILL4;

    while (q < end) {
        const int slice = q / TSLICE4;            // 0..111 = (batch-1)*16 + t
        int send = (slice + 1) * TSLICE4;
        if (send > end) send = end;
        float zv = 0.0f;
        if ((slice >> 4) == 6) {                  // batch 7
            const int t = slice & 15;
            float z = 0.0f;
            for (int i = 0; i < t; ++i) z = 3.0f - 0.4f * z;
            zv = z;
        }
        const float4 val = make_float4(zv, zv, zv, zv);
        for (int i = q + tid; i < send; i += 256)
            out4[i] = val;
        q = send;
    }
}

extern "C" void kernel_launch(void* const* d_in, const int* in_sizes, int n_in,
                              void* d_out, int out_size, void* d_ws, size_t ws_size,
                              hipStream_t stream) {
    const float* x = (const float*)d_in[0];
    float* out = (float*)d_out;
    temporal_fused<<<NTILES * 4 - 3 + (NFILL - (NTILES * 3 - 3)), 256, 0, stream>>>(x, out);
    // grid = 896: tile blocks at bid%4==0 (bid<784), 700 fill blocks elsewhere
}

// Round 3
// 17.836 us; speedup vs baseline: 1.3696x; 1.3696x over previous
//
#include <hip/hip_runtime.h>

// Problem geometry (f32):
//   x:   [8, 16, 3, 224, 224]
//   out: [8, 16, 224, 224, 3]  (permute 0,1,4,3,2)
// batch 0: y[0]=x[0]; y[t] = x[t] - 0.4*y[t-1] + 3   (elementwise c,h,w)
// batches 1..6: zeros
// batch 7: z[0]=0; z[t] = 3 - 0.4*z[t-1], broadcast over (w,h,c)
//
// Round 3: fix XCD imbalance. Blocks round-robin XCDs by bid%8; round-2's
// tiles at bid%4==0 put ALL 196 heavy tile blocks on XCDs {0,4} -> those two
// XCDs carried ~2.1x average traffic -> makespan ~21us. Tiles now at bid%9==0
// (9 coprime to 8) -> 24.5 tiles/XCD. Grid widened to 2048 blocks.

#define SP        150528    // 3*224*224 elements per (b,t) slice
#define TT        16
#define CH_STRIDE 50176     // 224*224
#define BSTRIDE   2408448   // 16*SP elements per batch

#define NWT    7            // w tiles (224/32)
#define NTILES 196          // 28 h-tiles x 7 w-tiles

#define FILL4   4214784     // 7 * 16*SP/4 float4s (batches 1..7)
#define TSLICE4 37632       // SP/4
#define NBLOCKS 2048
#define NFILL   (NBLOCKS - NTILES)   // 1852
#define RFILL   2276                 // ceil(FILL4/NFILL)
#define SPREAD  9                    // coprime to 8 -> uniform over XCDs

__global__ __launch_bounds__(256) void temporal_fused(
    const float* __restrict__ x, float* __restrict__ out)
{
    const int tid = threadIdx.x;
    const int bid = blockIdx.x;

    const bool is_tile = (bid % SPREAD == 0) && (bid / SPREAD) < NTILES;

    if (is_tile) {
        // ------------- batch-0 recurrence, tile = 8h x 32w, 3c/thread -----
        const int tileid = bid / SPREAD;
        const int h0 = (tileid / NWT) * 8;
        const int w0 = (tileid % NWT) * 32;
        const int dw = tid & 31;       // w offset: 32 consecutive -> 128B rows
        const int hh = tid >> 5;       // h offset 0..7
        const int rbase = (h0 + hh) * 224 + w0 + dw;

        // all 48 loads independent -> single HBM latency
        float v[TT][3];
        #pragma unroll
        for (int t = 0; t < TT; ++t) {
            #pragma unroll
            for (int c = 0; c < 3; ++c)
                v[t][c] = x[t * SP + c * CH_STRIDE + rbase];
        }

        const int ob = (w0 + dw) * 672 + (h0 + hh) * 3;
        float y0 = v[0][0], y1 = v[0][1], y2 = v[0][2];
        out[ob + 0] = y0;
        out[ob + 1] = y1;
        out[ob + 2] = y2;
        #pragma unroll
        for (int t = 1; t < TT; ++t) {
            y0 = v[t][0] - 0.4f * y0 + 3.0f;
            y1 = v[t][1] - 0.4f * y1 + 3.0f;
            y2 = v[t][2] - 0.4f * y2 + 3.0f;
            const int o = t * SP + ob;
            out[o + 0] = y0;
            out[o + 1] = y1;
            out[o + 2] = y2;
        }
        return;
    }

    // ---------------- fill: batches 1..6 zeros, batch 7 broadcast z[t] ----
    const int tiles_before = min((bid + SPREAD - 1) / SPREAD, NTILES);
    const int fidx = bid - tiles_before;          // 0..NFILL-1

    float4* out4 = reinterpret_cast<float4*>(out + BSTRIDE); // batch-1 start
    int q   = fidx * RFILL;
    int end = q + RFILL;
    if (end > FILL4) end = FILL4;

    while (q < end) {
        const int slice = q / TSLICE4;            // 0..111 = (batch-1)*16 + t
        int send = (slice + 1) * TSLICE4;
        if (send > end) send = end;
        float zv = 0.0f;
        if ((slice >> 4) == 6) {                  // batch 7
            const int t = slice & 15;
            float z = 0.0f;
            for (int i = 0; i < t; ++i) z = 3.0f - 0.4f * z;
            zv = z;
        }
        const float4 val = make_float4(zv, zv, zv, zv);
        for (int i = q + tid; i < send; i += 256)
            out4[i] = val;
        q = send;
    }
}

extern "C" void kernel_launch(void* const* d_in, const int* in_sizes, int n_in,
                              void* d_out, int out_size, void* d_ws, size_t ws_size,
                              hipStream_t stream) {
    const float* x = (const float*)d_in[0];
    float* out = (float*)d_out;
    temporal_fused<<<NBLOCKS, 256, 0, stream>>>(x, out);
}